// Round 5
// baseline (52.971 us; speedup 1.0000x reference)
//
#include <hip/hip_runtime.h>
#include <math.h>

#define L_BANDS 28
#define H 1024
#define W 1024
#define HW (H * W)

// 8B vector, 4B-alignment-safe (dx parity is data-dependent in general).
typedef float f2 __attribute__((ext_vector_type(2), aligned(4)));

// Pin 14 f2 values in registers via an identity volatile asm. The "+v"
// redefinition creates hard data deps: every load producing A[B+j] must
// precede this asm (and cannot sink past it: volatile asm = unknown memory),
// and every consumer must follow it. This is the MLP batching that
// sched_barrier(0) failed to enforce in rounds 3-4 (VGPR stayed 36).
#define PIN14(A, B) asm volatile("" \
    : "+v"((A)[(B) + 0]), "+v"((A)[(B) + 1]), "+v"((A)[(B) + 2]), \
      "+v"((A)[(B) + 3]), "+v"((A)[(B) + 4]), "+v"((A)[(B) + 5]), \
      "+v"((A)[(B) + 6]), "+v"((A)[(B) + 7]), "+v"((A)[(B) + 8]), \
      "+v"((A)[(B) + 9]), "+v"((A)[(B) + 10]), "+v"((A)[(B) + 11]), \
      "+v"((A)[(B) + 12]), "+v"((A)[(B) + 13]))

// Gather formulation: out[Y,X] = sum_l mask[Y-dy_l, X-dx_l] * x[l, Y-dy_l, X-dx_l]
// Offsets mirror the reference's detached numpy math (float64, rint).
__global__ __launch_bounds__(256, 3)
void cassi_fwd_pin(const float* __restrict__ x,
                   const float* __restrict__ mask,
                   const float* __restrict__ phi_deg,
                   const float* __restrict__ s_nom,
                   float* __restrict__ out,
                   int out_size) {
    __shared__ int s_dx[L_BANDS];
    __shared__ int s_dy[L_BANDS];
    __shared__ int s_off[L_BANDS];  // dy*W + dx (gather offset in x/mask space)
    __shared__ int s_Wp;
    __shared__ int s_dymax;

    if (threadIdx.x == 0) {
        double phi = (double)phi_deg[0] * 3.14159265358979323846 / 180.0;
        double c = cos(phi);
        double sn = sin(phi);
        double dxmin = 1e300, dymin = 1e300;
        for (int l = 0; l < L_BANDS; ++l) {
            double s = (double)s_nom[l];
            dxmin = fmin(dxmin, s * c);
            dymin = fmin(dymin, s * sn);
        }
        int dxmax = 0, dymax = 0;
        for (int l = 0; l < L_BANDS; ++l) {
            double s = (double)s_nom[l];
            int dx = (int)rint(s * c - dxmin);
            int dy = (int)rint(s * sn - dymin);
            s_dx[l] = dx;
            s_dy[l] = dy;
            s_off[l] = dy * W + dx;
            dxmax = max(dxmax, dx);
            dymax = max(dymax, dy);
        }
        s_Wp = W + dxmax;
        s_dymax = dymax;
    }
    __syncthreads();

    const int Wp = s_Wp;
    const int dxmax = Wp - W;
    const int dymax = s_dymax;

    int t0 = (blockIdx.x * blockDim.x + threadIdx.x) * 2;
    if (t0 >= out_size) return;

    int Y = t0 / Wp;
    int X0 = t0 - Y * Wp;

    if (Y >= dymax && Y < H && X0 >= dxmax && X0 <= W - 2) {
        // Interior: all 28 bands in-bounds for both pixels -> no checks.
        const int pbase = Y * W + X0;

        f2 xs[L_BANDS], ms[L_BANDS];
        // Issue all 56 loads back-to-back.
#pragma unroll
        for (int l = 0; l < L_BANDS; ++l) {
            const int p = pbase - s_off[l];
            xs[l] = *(const f2*)(x + l * HW + p);
            ms[l] = *(const f2*)(mask + p);
        }
        // Hard pin: all loads issued before this point, all FMAs after.
        PIN14(xs, 0);
        PIN14(xs, 14);
        PIN14(ms, 0);
        PIN14(ms, 14);

        f2 acc = {0.f, 0.f};
#pragma unroll
        for (int l = 0; l < L_BANDS; ++l) {
            acc += ms[l] * xs[l];
        }
        *(f2*)(out + t0) = acc;  // t0 even -> 8B-aligned target (4B-safe type)
    } else {
        // Edge path: per-pixel with bounds checks.
        for (int k = 0; k < 2; ++k) {
            int i = t0 + k;
            if (i >= out_size) break;
            int Yk = i / Wp;
            int Xk = i - Yk * Wp;
            float a = 0.0f;
#pragma unroll
            for (int l = 0; l < L_BANDS; ++l) {
                int h = Yk - s_dy[l];
                int w = Xk - s_dx[l];
                if ((unsigned)h < (unsigned)H && (unsigned)w < (unsigned)W) {
                    int p = h * W + w;
                    a = fmaf(mask[p], x[l * HW + p], a);
                }
            }
            out[i] = a;
        }
    }
}

extern "C" void kernel_launch(void* const* d_in, const int* in_sizes, int n_in,
                              void* d_out, int out_size, void* d_ws, size_t ws_size,
                              hipStream_t stream) {
    const float* x = (const float*)d_in[0];      // [1, 28, 1024, 1024]
    const float* mask = (const float*)d_in[1];   // [1024, 1024]
    const float* phi = (const float*)d_in[2];    // [1]
    const float* s_nom = (const float*)d_in[3];  // [28]
    float* out = (float*)d_out;                  // [1, Hp, Wp]

    const int threads = 256;
    const int tiles = (out_size + 1) / 2;
    const int blocks = (tiles + threads - 1) / threads;
    cassi_fwd_pin<<<blocks, threads, 0, stream>>>(x, mask, phi, s_nom, out, out_size);
}

// Round 6
// 38.383 us; speedup vs baseline: 1.3801x; 1.3801x over previous
//
#include <hip/hip_runtime.h>
#include <math.h>

#define NL 28
#define H 1024
#define W 1024
#define HW (H * W)
#define CHUNK 252         // output px per block
#define XROW 256          // floats staged per band (1024 B = 1 global_load_lds x16)
#define MROW 832          // padded mask row: [0,64) zeros | [64,576) data | [576,832) zeros
#define MOFF 64
#define MDATA 512
#define MB_ROWS 2         // fast path supports dymax <= 1

typedef __attribute__((address_space(1))) const void GV;
typedef __attribute__((address_space(3))) void LV;

// Async global->LDS: dest is WAVE-UNIFORM base; HW writes lane i's 16B to
// base + i*16. No dest VGPRs -> deep MLP without fighting the regalloc
// (rounds 2-5 showed the compiler collapses register-staged MLP to ~2).
__device__ __forceinline__ void gl_lds16(const float* g, float* l) {
    __builtin_amdgcn_global_load_lds((GV*)g, (LV*)l, 16, 0, 0);
}

// out[Y,X] = sum_l mask[Y-dy_l, X-dx_l] * x[l, Y-dy_l, X-dx_l]
// Per block: stage band rows + guard-padded mask rows into LDS, one barrier,
// then per-px: 28 x (pack ds_read + x ds_read + m ds_read + fma). OOB columns
// hit zeroed mask guard bands -> contribute 0 with no compares.
__global__ __launch_bounds__(256)
void cassi_v6(const float* __restrict__ x, const float* __restrict__ mask,
              const float* __restrict__ phi_deg, const float* __restrict__ s_nom,
              float* __restrict__ out, int out_size)
{
    __shared__ float xbuf[NL][XROW];
    __shared__ float mbuf[MB_ROWS][MROW];
    __shared__ int s_dx[NL], s_dy[NL], s_xs[NL];
    __shared__ unsigned s_pack[NL];
    __shared__ int s_geom[8];  // 0:Wp 1:Hp 2:nchunk 3:dxmax 4:dymax

    const int tid = threadIdx.x;

    // ---- offsets: wave 0, lane-parallel (float math; rint boundaries are
    // >0.008 away for any plausible input scale, float error ~1e-6) ----
    if (tid < 64) {
        float phi = phi_deg[0] * 0.017453292519943295f;
        float c = cosf(phi), sn = sinf(phi);
        float s = (tid < NL) ? s_nom[tid] : 0.f;
        float dxv = s * c, dyv = s * sn;
        float dxm = (tid < NL) ? dxv : 3.0e38f;
        float dym = (tid < NL) ? dyv : 3.0e38f;
        for (int d = 1; d < 64; d <<= 1) {
            dxm = fminf(dxm, __shfl_xor(dxm, d, 64));
            dym = fminf(dym, __shfl_xor(dym, d, 64));
        }
        int dxi = (tid < NL) ? (int)rintf(dxv - dxm) : 0;
        int dyi = (tid < NL) ? (int)rintf(dyv - dym) : 0;
        int dxmax = dxi, dymax = dyi;
        for (int d = 1; d < 64; d <<= 1) {
            dxmax = max(dxmax, __shfl_xor(dxmax, d, 64));
            dymax = max(dymax, __shfl_xor(dymax, d, 64));
        }
        if (tid < NL) { s_dx[tid] = dxi; s_dy[tid] = dyi; }
        if (tid == 0) {
            int Wp = W + dxmax;
            s_geom[0] = Wp;
            s_geom[1] = out_size / Wp;            // Hp (exact)
            s_geom[2] = (Wp + CHUNK - 1) / CHUNK; // nchunk
            s_geom[3] = dxmax;
            s_geom[4] = dymax;
        }
    }
    __syncthreads();

    const int Wp = s_geom[0], Hp = s_geom[1], nchunk = s_geom[2];
    const int dxmax = s_geom[3], dymax = s_geom[4];
    const int bid = blockIdx.x;
    const int Y = bid / nchunk;
    const int X0 = (bid - Y * nchunk) * CHUNK;
    if (Y >= Hp) return;  // over-provisioned grid; uniform exit

    const bool fast = (dymax < MB_ROWS) && (dxmax <= MOFF) && (Y >= dymax) && (Y < H);

    if (!fast) {
        // Edge rows (Y < dymax or Y >= H) or unsupported geometry: checked path.
        for (int i = tid; i < CHUNK; i += 256) {
            int X = X0 + i;
            if (X >= Wp) break;
            float a = 0.f;
            for (int l = 0; l < NL; ++l) {
                int h = Y - s_dy[l], w = X - s_dx[l];
                if ((unsigned)h < (unsigned)H && (unsigned)w < (unsigned)W) {
                    int p = h * W + w;
                    a = fmaf(mask[p], x[(size_t)l * HW + p], a);
                }
            }
            out[(size_t)Y * Wp + X] = a;
        }
        return;
    }

    // Mask staging window: 512 floats from aligned, clamped start.
    int mclamp = (X0 - dxmax) & ~3;
    mclamp = min(max(mclamp, 0), W - MDATA);

    // Per-band constants, packed: [31:16] flat mbuf offset, [7:0] xbuf offset mod 256.
    if (tid < NL) {
        int dx = s_dx[tid], dy = s_dy[tid];
        int xs = (X0 - dx) & ~3;
        xs = min(max(xs, 0), W - XROW);
        s_xs[tid] = xs;
        int idxb = X0 - dx - xs;                       // may be negative (wraps to masked px)
        int moff = dy * MROW + MOFF + (X0 - dx - mclamp);
        s_pack[tid] = ((unsigned)moff << 16) | ((unsigned)idxb & 255u);
    }
    __syncthreads();

    // ---- async staging: x bands (7 per wave) + mask rows (wave dy) ----
    const int lane = tid & 63, wid = tid >> 6;
#pragma unroll
    for (int j = 0; j < 7; ++j) {
        int l = wid * 7 + j;
        int xs = s_xs[l], dy = s_dy[l];
        const float* src = x + (size_t)l * HW + (size_t)(Y - dy) * W + xs + lane * 4;
        gl_lds16(src, &xbuf[l][0]);
    }
    if (wid <= dymax) {  // wave r stages mask row Y-r (2 x 1024 B)
        const float* src = mask + (size_t)(Y - wid) * W + mclamp + lane * 4;
        gl_lds16(src, &mbuf[wid][MOFF]);
        gl_lds16(src + 256, &mbuf[wid][MOFF + 256]);
    }
    // Zero guard bands (disjoint from async-staged data region).
    for (int j = tid; j < MB_ROWS * MROW; j += 256) {
        int r = (j >= MROW) ? 1 : 0;
        int c = j - r * MROW;
        if (c < MOFF || c >= MOFF + MDATA) mbuf[r][c] = 0.f;
    }
    __syncthreads();  // drains vmcnt (global_load_lds) + lgkm before barrier

    // ---- compute: 1 px/thread ----
    float acc = 0.f;
    const float* mflat = &mbuf[0][0];
#pragma unroll
    for (int l = 0; l < NL; ++l) {
        unsigned pk = s_pack[l];
        int xi = (int)((pk + (unsigned)tid) & 255u);   // wraps only for masked/unstored px
        int mi = (int)(pk >> 16) + tid;                // OOB w -> guard zeros
        acc = fmaf(xbuf[l][xi], mflat[mi], acc);
    }
    if (tid < CHUNK) {
        int X = X0 + tid;
        if (X < Wp) out[(size_t)Y * Wp + X] = acc;
    }
}

extern "C" void kernel_launch(void* const* d_in, const int* in_sizes, int n_in,
                              void* d_out, int out_size, void* d_ws, size_t ws_size,
                              hipStream_t stream) {
    const float* x = (const float*)d_in[0];      // [1, 28, 1024, 1024]
    const float* mask = (const float*)d_in[1];   // [1024, 1024]
    const float* phi = (const float*)d_in[2];    // [1]
    const float* s_nom = (const float*)d_in[3];  // [28]
    float* out = (float*)d_out;                  // [1, Hp, Wp]

    // Host doesn't know Wp; bound blocks = Hp*ceil(Wp/CHUNK) <= out/CHUNK + out/1024.
    const int blocks = (out_size + CHUNK - 1) / CHUNK + (out_size + 1023) / 1024;
    cassi_v6<<<blocks, 256, 0, stream>>>(x, mask, phi, s_nom, out, out_size);
}